// Round 7
// baseline (287.252 us; speedup 1.0000x reference)
//
#include <hip/hip_runtime.h>
#include <math.h>

#define CAP 48     // max bucketed in-degree; Poisson(16), P(deg>=48) ~ 8e-11/node
#define NPART 8    // dst partitions ~ XCDs

typedef float f32x4 __attribute__((ext_vector_type(4)));
typedef __bf16 bf16x8 __attribute__((ext_vector_type(8)));
typedef unsigned short ushort8 __attribute__((ext_vector_type(8)));
typedef int i32x4 __attribute__((ext_vector_type(4)));
typedef int i32x2 __attribute__((ext_vector_type(2)));

__device__ __forceinline__ float leaky(float x){ return x > 0.f ? x : 0.2f * x; }
__device__ __forceinline__ float eluf(float x){ return x > 0.f ? x : __expf(x) - 1.f; }
__device__ __forceinline__ unsigned short f2bf(float f){  // RNE float->bf16
  unsigned u = __float_as_uint(f);
  u += 0x7FFF + ((u >> 16) & 1);
  return (unsigned short)(u >> 16);
}

// K1: compute vw in LDS, emit packed 64B node record:
// rec[n] = {x0..x5, as0..as3, ad0..ad3, pad, pad}  (4 x float4)
// Also (first 64 blocks) pre-pack W2 into bf16 MFMA B-fragment lane order.
__global__ __launch_bounds__(256) void k1_att1(const float* __restrict__ x,
    const float* __restrict__ W1, const float* __restrict__ as1,
    const float* __restrict__ ad1, const float* __restrict__ W2,
    unsigned short* __restrict__ Bfrag, float4* __restrict__ rec, int N){
  __shared__ float vw[48];
  int t = threadIdx.x;
  int gid = blockIdx.x * 256 + t;
  if (gid < 16384){
    int j  = gid & 7;
    int L  = (gid >> 3) & 63;
    int ct = (gid >> 9) & 3;
    int ks = gid >> 11;
    int k = ks*32 + ((L >> 4) & 3)*8 + j;
    int c = ct*16 + (L & 15);
    Bfrag[gid] = f2bf(W2[k*64 + c]);
  }
  if (t < 48){
    int side = t / 24, r = t % 24, f = r / 4, h = r % 4;
    const float* att = side ? ad1 : as1;
    float s = 0.f;
    for (int c = 0; c < 64; ++c) s += W1[f*256 + h*64 + c] * att[h*64 + c];
    vw[side*24 + f*4 + h] = s;
  }
  __syncthreads();
  int n = gid;
  if (n >= N) return;
  float xf[6];
  for (int f = 0; f < 6; ++f) xf[f] = x[n*6 + f];
  float as[4], ad[4];
  for (int h = 0; h < 4; ++h){
    float s = 0.f, d = 0.f;
    for (int f = 0; f < 6; ++f){ s += xf[f] * vw[f*4 + h]; d += xf[f] * vw[24 + f*4 + h]; }
    as[h] = s; ad[h] = d;
  }
  rec[n*4 + 0] = make_float4(xf[0], xf[1], xf[2], xf[3]);
  rec[n*4 + 1] = make_float4(xf[4], xf[5], as[0], as[1]);
  rec[n*4 + 2] = make_float4(as[2], as[3], ad[0], ad[1]);
  rec[n*4 + 3] = make_float4(ad[2], ad[3], 0.f, 0.f);
}

// K2a: route edges into 8 per-partition (dst/part) queues of (dst,src) pairs.
// Single pass over the edge stream (vs R5's 8 passes = 50MB HBM re-fetch).
// Block-level binning: LDS-atomic rank + one global tail atomic per partition
// per block-iter (~2k/address total — contention-free). Queue aliases h2.
__global__ __launch_bounds__(256) void k2a_route(const int* __restrict__ ei,
    int E, int part, int QCAP, i32x2* __restrict__ queue, int* __restrict__ qtail){
  __shared__ int lcnt[NPART];
  __shared__ int lbase[NPART];
  int t = threadIdx.x;
  int E4 = E >> 2;
  if (blockIdx.x == 0 && t < (E & 3)){   // remainder edges: direct path
    int e = E4*4 + t;
    int src = ei[e], dst = ei[E + e];
    int p = min((int)((unsigned)dst / (unsigned)part), NPART-1);
    int slot = atomicAdd(&qtail[p], 1);
    if (slot < QCAP){ i32x2 v = {dst, src}; queue[(size_t)p*QCAP + slot] = v; }
  }
  const i32x4* s4 = (const i32x4*)ei;
  const i32x4* d4 = (const i32x4*)(ei + E);
  int stride = gridDim.x * 256;
  int nit = (E4 + stride - 1) / stride;
  for (int it = 0; it < nit; ++it){
    int i = it*stride + blockIdx.x*256 + t;
    bool valid = i < E4;
    i32x4 s = {0,0,0,0}, d = {0,0,0,0};
    if (valid){
      s = __builtin_nontemporal_load(s4 + i);
      d = __builtin_nontemporal_load(d4 + i);
    }
    if (t < NPART) lcnt[t] = 0;
    __syncthreads();
    int p[4], r[4];
    #pragma unroll
    for (int j = 0; j < 4; ++j){
      if (valid){
        p[j] = min((int)((unsigned)d[j] / (unsigned)part), NPART-1);
        r[j] = atomicAdd(&lcnt[p[j]], 1);
      }
    }
    __syncthreads();
    if (t < NPART && lcnt[t] > 0) lbase[t] = atomicAdd(&qtail[t], lcnt[t]);
    __syncthreads();
    if (valid){
      #pragma unroll
      for (int j = 0; j < 4; ++j){
        int slot = lbase[p[j]] + r[j];
        if (slot < QCAP){ i32x2 v = {d[j], s[j]}; queue[(size_t)p[j]*QCAP + slot] = v; }
      }
    }
    __syncthreads();
  }
}

// K2b: build buckets from per-partition queues. blockIdx&7 == partition == XCD
// (round-robin heuristic): sequential 1.6MB queue read + scatter confined to
// a 2.45MB slab that should stay resident in that XCD's L2.
__global__ __launch_bounds__(256) void k2b_build(const i32x2* __restrict__ queue,
    const int* __restrict__ qtail, int QCAP, int* __restrict__ cnt,
    int* __restrict__ bucket){
  int p = blockIdx.x & (NPART-1);
  int g = blockIdx.x >> 3;
  int nb = gridDim.x >> 3;
  int n = qtail[p]; if (n > QCAP) n = QCAP;
  const i32x2* q = queue + (size_t)p*QCAP;
  for (int i = g*256 + threadIdx.x; i < n; i += nb*256){
    i32x2 pr = __builtin_nontemporal_load(q + i);
    int pos = atomicAdd(&cnt[pr.x], 1);
    if (pos < CAP) bucket[(size_t)pr.x*CAP + pos] = pr.y;
  }
}

// K3: per-NODE layer-1 softmax-aggregate in input space, all 4 heads at once.
// Output packed 128B/node: aggr[n*32 + h*6 + f] = acc, aggr[n*32 + 24 + h] = den.
__global__ __launch_bounds__(256) void k3_agg1(const float4* __restrict__ rec,
    const int* __restrict__ cnt, const int* __restrict__ bucket,
    float* __restrict__ aggr, int N){
  int n = blockIdx.x * 256 + threadIdx.x;
  if (n >= N) return;
  float4 q0 = rec[n*4+0], q1 = rec[n*4+1], q2 = rec[n*4+2], q3 = rec[n*4+3];
  float xf[6] = {q0.x, q0.y, q0.z, q0.w, q1.x, q1.y};
  float as[4] = {q1.z, q1.w, q2.x, q2.y};
  float ad[4] = {q2.z, q2.w, q3.x, q3.y};
  float acc[4][6], den[4];
  for (int h = 0; h < 4; ++h){
    float e0 = __expf(leaky(as[h] + ad[h]));   // self-loop
    den[h] = e0;
    for (int f = 0; f < 6; ++f) acc[h][f] = e0 * xf[f];
  }
  int deg = min(cnt[n], CAP);
  const int* bk = bucket + (size_t)n*CAP;
  int i = 0;
  for (; i + 2 <= deg; i += 2){
    int s0 = bk[i], s1 = bk[i+1];
    float4 a0 = rec[s0*4+0], a1 = rec[s0*4+1], a2 = rec[s0*4+2];
    float4 b0 = rec[s1*4+0], b1 = rec[s1*4+1], b2 = rec[s1*4+2];
    float sx0[6] = {a0.x, a0.y, a0.z, a0.w, a1.x, a1.y};
    float sa0[4] = {a1.z, a1.w, a2.x, a2.y};
    float sx1[6] = {b0.x, b0.y, b0.z, b0.w, b1.x, b1.y};
    float sa1[4] = {b1.z, b1.w, b2.x, b2.y};
    for (int h = 0; h < 4; ++h){
      float e0 = __expf(leaky(sa0[h] + ad[h]));
      float e1 = __expf(leaky(sa1[h] + ad[h]));
      den[h] += e0 + e1;
      for (int f = 0; f < 6; ++f) acc[h][f] += e0 * sx0[f] + e1 * sx1[f];
    }
  }
  if (i < deg){
    int s = bk[i];
    float4 a0 = rec[s*4+0], a1 = rec[s*4+1], a2 = rec[s*4+2];
    float sx[6] = {a0.x, a0.y, a0.z, a0.w, a1.x, a1.y};
    float sa[4] = {a1.z, a1.w, a2.x, a2.y};
    for (int h = 0; h < 4; ++h){
      float e = __expf(leaky(sa[h] + ad[h]));
      den[h] += e;
      for (int f = 0; f < 6; ++f) acc[h][f] += e * sx[f];
    }
  }
  float4* o = (float4*)(aggr + (size_t)n*32);
  o[0] = make_float4(acc[0][0], acc[0][1], acc[0][2], acc[0][3]);
  o[1] = make_float4(acc[0][4], acc[0][5], acc[1][0], acc[1][1]);
  o[2] = make_float4(acc[1][2], acc[1][3], acc[1][4], acc[1][5]);
  o[3] = make_float4(acc[2][0], acc[2][1], acc[2][2], acc[2][3]);
  o[4] = make_float4(acc[2][4], acc[2][5], acc[3][0], acc[3][1]);
  o[5] = make_float4(acc[3][2], acc[3][3], acc[3][4], acc[3][5]);
  o[6] = make_float4(den[0], den[1], den[2], den[3]);
}

// K4 (MFMA): per-wave 16 nodes. A-frag (helu1, bf16) computed in registers
// from aggr+W1+b1; B-frags (W2) pre-packed in lane order; no LDS, no barriers.
__global__ __launch_bounds__(256) void k4_mfma(
    const float* __restrict__ aggr, const float* __restrict__ W1,
    const float* __restrict__ b1, const unsigned short* __restrict__ Bfrag,
    const float* __restrict__ as2v, const float* __restrict__ ad2v,
    float* __restrict__ h2, float2* __restrict__ a2, int N){
  int t = threadIdx.x;
  int L = t & 63;
  int w = t >> 6;
  int base = blockIdx.x * 64;
  int m = L & 15;
  int quad = L >> 4;
  int na = base + w*16 + m;
  int nc = min(na, N-1);
  const float4* A4 = (const float4*)(aggr + (size_t)nc*32);
  float4 q0=A4[0], q1=A4[1], q2=A4[2], q3=A4[3], q4=A4[4], q5=A4[5], q6=A4[6];
  float d0=1.f/q6.x, d1=1.f/q6.y, d2=1.f/q6.z, d3=1.f/q6.w;
  float af[24];
  af[0]=q0.x*d0;  af[1]=q0.y*d0;  af[2]=q0.z*d0;  af[3]=q0.w*d0;  af[4]=q1.x*d0;  af[5]=q1.y*d0;
  af[6]=q1.z*d1;  af[7]=q1.w*d1;  af[8]=q2.x*d1;  af[9]=q2.y*d1;  af[10]=q2.z*d1; af[11]=q2.w*d1;
  af[12]=q3.x*d2; af[13]=q3.y*d2; af[14]=q3.z*d2; af[15]=q3.w*d2; af[16]=q4.x*d2; af[17]=q4.y*d2;
  af[18]=q4.z*d3; af[19]=q4.w*d3; af[20]=q5.x*d3; af[21]=q5.y*d3; af[22]=q5.z*d3; af[23]=q5.w*d3;

  f32x4 acc[4];
  #pragma unroll
  for (int ct = 0; ct < 4; ++ct) acc[ct] = (f32x4){0.f, 0.f, 0.f, 0.f};

  #pragma unroll
  for (int ks = 0; ks < 8; ++ks){
    int kb = ks*32 + quad*8;
    int kc = kb >> 6;
    const float* afk = af + kc*6;
    float4 bb0 = *(const float4*)(b1 + kb);
    float4 bb1 = *(const float4*)(b1 + kb + 4);
    float s0=bb0.x, s1=bb0.y, s2=bb0.z, s3=bb0.w;
    float s4=bb1.x, s5=bb1.y, s6=bb1.z, s7=bb1.w;
    #pragma unroll
    for (int f = 0; f < 6; ++f){
      float a = afk[f];
      float4 w0 = *(const float4*)(W1 + f*256 + kb);
      float4 w1 = *(const float4*)(W1 + f*256 + kb + 4);
      s0 += a*w0.x; s1 += a*w0.y; s2 += a*w0.z; s3 += a*w0.w;
      s4 += a*w1.x; s5 += a*w1.y; s6 += a*w1.z; s7 += a*w1.w;
    }
    ushort8 ap;
    ap[0]=f2bf(eluf(s0)); ap[1]=f2bf(eluf(s1)); ap[2]=f2bf(eluf(s2)); ap[3]=f2bf(eluf(s3));
    ap[4]=f2bf(eluf(s4)); ap[5]=f2bf(eluf(s5)); ap[6]=f2bf(eluf(s6)); ap[7]=f2bf(eluf(s7));
    bf16x8 av = __builtin_bit_cast(bf16x8, ap);
    #pragma unroll
    for (int ct = 0; ct < 4; ++ct){
      bf16x8 bv = *(const bf16x8*)(Bfrag + (size_t)(((ks*4 + ct)*64 + L) * 8));
      acc[ct] = __builtin_amdgcn_mfma_f32_16x16x32_bf16(av, bv, acc[ct], 0, 0, 0);
    }
  }

  float asv[4], adv[4];
  #pragma unroll
  for (int ct = 0; ct < 4; ++ct){ asv[ct] = as2v[ct*16 + m]; adv[ct] = ad2v[ct*16 + m]; }
  float ps[4] = {0,0,0,0}, pd[4] = {0,0,0,0};
  #pragma unroll
  for (int ct = 0; ct < 4; ++ct)
    #pragma unroll
    for (int r = 0; r < 4; ++r){
      ps[r] += acc[ct][r] * asv[ct];
      pd[r] += acc[ct][r] * adv[ct];
    }
  #pragma unroll
  for (int r = 0; r < 4; ++r){
    int nr = base + w*16 + quad*4 + r;
    if (nr < N){
      #pragma unroll
      for (int ct = 0; ct < 4; ++ct)
        h2[(size_t)nr*64 + ct*16 + m] = acc[ct][r];
    }
  }
  #pragma unroll
  for (int mask = 1; mask <= 8; mask <<= 1){
    #pragma unroll
    for (int r = 0; r < 4; ++r){
      ps[r] += __shfl_xor(ps[r], mask, 64);
      pd[r] += __shfl_xor(pd[r], mask, 64);
    }
  }
  if (m == 0){
    #pragma unroll
    for (int r = 0; r < 4; ++r){
      int nr = base + w*16 + quad*4 + r;
      if (nr < N) a2[nr] = make_float2(ps[r], pd[r]);
    }
  }
}

// K5: layer-2 aggregation only for drone dsts (first ND) + elu + MLP head.
__global__ __launch_bounds__(256) void k5_out(
    const float* __restrict__ h2, const float2* __restrict__ a2,
    const int* __restrict__ cnt, const int* __restrict__ bucket,
    const float* __restrict__ b2, const float* __restrict__ fc1w,
    const float* __restrict__ fc1b, const float* __restrict__ fc2w,
    const float* __restrict__ fc2b, float* __restrict__ out, int ND){
  __shared__ float hb[4][64];
  int lane = threadIdx.x & 63;
  int w = threadIdx.x >> 6;
  int n = blockIdx.x * 4 + w;
  if (n >= ND) return;
  float2 self = a2[n];
  float adv = self.y;
  float e0 = __expf(leaky(self.x + adv));
  float den = e0;
  float acc = e0 * h2[n*64 + lane];
  int deg = min(cnt[n], CAP);
  for (int i = 0; i < deg; ++i){
    int s = bucket[(size_t)n*CAP + i];
    float e = __expf(leaky(a2[s].x + adv));
    den += e;
    acc += e * h2[s*64 + lane];
  }
  float hv = eluf(acc / den + b2[lane]);
  hb[w][lane] = hv;               // wave-local LDS (lockstep wave64)
  float t1 = fc1b[lane];
  for (int k = 0; k < 64; ++k) t1 += hb[w][k] * fc1w[k*64 + lane];
  t1 = fmaxf(t1, 0.f);
  float p0 = t1 * fc2w[lane*2 + 0];
  float p1 = t1 * fc2w[lane*2 + 1];
  for (int o = 32; o > 0; o >>= 1){
    p0 += __shfl_down(p0, o, 64);
    p1 += __shfl_down(p1, o, 64);
  }
  if (lane == 0){
    out[n*2 + 0] = tanhf(p0 + fc2b[0]) * 2.f;
    out[n*2 + 1] = tanhf(p1 + fc2b[1]) * 2.f;
  }
}

extern "C" void kernel_launch(void* const* d_in, const int* in_sizes, int n_in,
                              void* d_out, int out_size, void* d_ws, size_t ws_size,
                              hipStream_t stream){
  const float* x    = (const float*)d_in[0];
  const int*   ei   = (const int*)d_in[1];    // harness passes integers as int32
  const float* W1   = (const float*)d_in[3];
  const float* as1  = (const float*)d_in[4];
  const float* ad1  = (const float*)d_in[5];
  const float* b1   = (const float*)d_in[6];
  const float* W2   = (const float*)d_in[7];
  const float* as2  = (const float*)d_in[8];
  const float* ad2  = (const float*)d_in[9];
  const float* b2   = (const float*)d_in[10];
  const float* fc1w = (const float*)d_in[11];
  const float* fc1b = (const float*)d_in[12];
  const float* fc2w = (const float*)d_in[13];
  const float* fc2b = (const float*)d_in[14];
  float* out = (float*)d_out;

  int N  = in_sizes[0] / 6;
  int E  = in_sizes[1] / 2;
  int ND = out_size / 2;

  char* p = (char*)d_ws;
  auto alloc = [&](size_t bytes){ void* r = (void*)p; p += (bytes + 255) & ~(size_t)255; return r; };
  int*            cnt    = (int*)           alloc((size_t)N * 4 + 256); // + qtail[8]
  int*            qtail  = cnt + N;
  int*            bucket = (int*)           alloc((size_t)N * CAP * 4);
  float4*         rec    = (float4*)        alloc((size_t)N * 64);
  float*          aggr   = (float*)         alloc((size_t)N * 128);
  float*          h2     = (float*)         alloc((size_t)N * 256);
  float2*         a2     = (float2*)        alloc((size_t)N * 8);
  unsigned short* Bfrag  = (unsigned short*)alloc(16384 * 2);

  size_t needed = (size_t)(p - (char*)d_ws);
  if (needed > ws_size) return;   // clean fail instead of GPU fault

  // per-partition queues alias h2 (h2 written only later, by k4)
  int QCAP = (int)(((size_t)N * 256) / (NPART * sizeof(i32x2)));  // = N*4
  i32x2* queue = (i32x2*)h2;
  int part = (N + NPART - 1) / NPART;

  (void)hipMemsetAsync(cnt, 0, (size_t)N * 4 + 64, stream);  // cnt + qtail
  k1_att1<<<(N + 255)/256, 256, 0, stream>>>(x, W1, as1, ad1, W2, Bfrag, rec, N);
  k2a_route<<<1024, 256, 0, stream>>>(ei, E, part, QCAP, queue, qtail);
  k2b_build<<<1024, 256, 0, stream>>>(queue, qtail, QCAP, cnt, bucket);
  k3_agg1<<<(N + 255)/256, 256, 0, stream>>>(rec, cnt, bucket, aggr, N);
  k4_mfma<<<(N + 63)/64, 256, 0, stream>>>(aggr, W1, b1, Bfrag, as2, ad2, h2, a2, N);
  k5_out<<<(ND + 3)/4, 256, 0, stream>>>(h2, a2, cnt, bucket, b2,
                                         fc1w, fc1b, fc2w, fc2b, out, ND);
}

// Round 8
// 282.727 us; speedup vs baseline: 1.0160x; 1.0160x over previous
//
#include <hip/hip_runtime.h>
#include <math.h>

#define CAP 48     // max bucketed in-degree; Poisson(16), P(deg>=48) ~ 8e-11/node

typedef float f32x4 __attribute__((ext_vector_type(4)));
typedef __bf16 bf16x8 __attribute__((ext_vector_type(8)));
typedef unsigned short ushort8 __attribute__((ext_vector_type(8)));

__device__ __forceinline__ float leaky(float x){ return x > 0.f ? x : 0.2f * x; }
__device__ __forceinline__ float eluf(float x){ return x > 0.f ? x : __expf(x) - 1.f; }
__device__ __forceinline__ unsigned short f2bf(float f){  // RNE float->bf16
  unsigned u = __float_as_uint(f);
  u += 0x7FFF + ((u >> 16) & 1);
  return (unsigned short)(u >> 16);
}

// K1: compute vw in LDS, emit packed 64B node record:
// rec[n] = {x0..x5, as0..as3, ad0..ad3, pad, pad}  (4 x float4)
// Also (first 64 blocks) pre-pack W2 into bf16 MFMA B-fragment lane order.
__global__ __launch_bounds__(256) void k1_att1(const float* __restrict__ x,
    const float* __restrict__ W1, const float* __restrict__ as1,
    const float* __restrict__ ad1, const float* __restrict__ W2,
    unsigned short* __restrict__ Bfrag, float4* __restrict__ rec, int N){
  __shared__ float vw[48];
  int t = threadIdx.x;
  int gid = blockIdx.x * 256 + t;
  if (gid < 16384){
    int j  = gid & 7;
    int L  = (gid >> 3) & 63;
    int ct = (gid >> 9) & 3;
    int ks = gid >> 11;
    int k = ks*32 + ((L >> 4) & 3)*8 + j;
    int c = ct*16 + (L & 15);
    Bfrag[gid] = f2bf(W2[k*64 + c]);
  }
  if (t < 48){
    int side = t / 24, r = t % 24, f = r / 4, h = r % 4;
    const float* att = side ? ad1 : as1;
    float s = 0.f;
    for (int c = 0; c < 64; ++c) s += W1[f*256 + h*64 + c] * att[h*64 + c];
    vw[side*24 + f*4 + h] = s;
  }
  __syncthreads();
  int n = gid;
  if (n >= N) return;
  float xf[6];
  for (int f = 0; f < 6; ++f) xf[f] = x[n*6 + f];
  float as[4], ad[4];
  for (int h = 0; h < 4; ++h){
    float s = 0.f, d = 0.f;
    for (int f = 0; f < 6; ++f){ s += xf[f] * vw[f*4 + h]; d += xf[f] * vw[24 + f*4 + h]; }
    as[h] = s; ad[h] = d;
  }
  rec[n*4 + 0] = make_float4(xf[0], xf[1], xf[2], xf[3]);
  rec[n*4 + 1] = make_float4(xf[4], xf[5], as[0], as[1]);
  rec[n*4 + 2] = make_float4(as[2], as[3], ad[0], ad[1]);
  rec[n*4 + 3] = make_float4(ad[2], ad[3], 0.f, 0.f);
}

// K2: bucket build, single pass, 8-deep batched atomics.
// R7 evidence: the scatter is LATENCY-bound (1.08TB/s, VALU 0.6%), not BW-bound
// — write amplification is intrinsic to random scatter (multi-XCD partial-line
// writebacks) and costs no time. So: maximize outstanding atomics per thread.
// Phase 1: 8 independent NT loads; phase 2: 8 independent atomicAdds (all in
// flight); phase 3: 8 stores. No routing passes.
__global__ __launch_bounds__(256) void k2_bucket(const int* __restrict__ ei,
    int E, int* __restrict__ cnt, int* __restrict__ bucket){
  int base = blockIdx.x * 256 + threadIdx.x;
  int stride = gridDim.x * 256;
  for (int start = 0; start < E; start += stride * 8){
    int d[8], s[8], pos[8];
    #pragma unroll
    for (int j = 0; j < 8; ++j){
      int e = start + j*stride + base;
      bool v = e < E;
      d[j] = v ? __builtin_nontemporal_load(ei + E + e) : -1;
      s[j] = v ? __builtin_nontemporal_load(ei + e) : 0;
    }
    #pragma unroll
    for (int j = 0; j < 8; ++j)
      if (d[j] >= 0) pos[j] = atomicAdd(&cnt[d[j]], 1);
    #pragma unroll
    for (int j = 0; j < 8; ++j)
      if (d[j] >= 0 && pos[j] < CAP) bucket[(size_t)d[j]*CAP + pos[j]] = s[j];
  }
}

// K3: per-NODE layer-1 softmax-aggregate in input space, all 4 heads at once.
// 4-edge batched gathers (12 independent float4 loads in flight).
// Output packed 128B/node: aggr[n*32 + h*6 + f] = acc, aggr[n*32 + 24 + h] = den.
__global__ __launch_bounds__(256) void k3_agg1(const float4* __restrict__ rec,
    const int* __restrict__ cnt, const int* __restrict__ bucket,
    float* __restrict__ aggr, int N){
  int n = blockIdx.x * 256 + threadIdx.x;
  if (n >= N) return;
  float4 q0 = rec[n*4+0], q1 = rec[n*4+1], q2 = rec[n*4+2], q3 = rec[n*4+3];
  float xf[6] = {q0.x, q0.y, q0.z, q0.w, q1.x, q1.y};
  float as[4] = {q1.z, q1.w, q2.x, q2.y};
  float ad[4] = {q2.z, q2.w, q3.x, q3.y};
  float acc[4][6], den[4];
  for (int h = 0; h < 4; ++h){
    float e0 = __expf(leaky(as[h] + ad[h]));   // self-loop
    den[h] = e0;
    for (int f = 0; f < 6; ++f) acc[h][f] = e0 * xf[f];
  }
  int deg = min(cnt[n], CAP);
  const int* bk = bucket + (size_t)n*CAP;
  int i = 0;
  for (; i + 4 <= deg; i += 4){
    int sid[4];
    #pragma unroll
    for (int j = 0; j < 4; ++j) sid[j] = bk[i+j];
    float4 ra[4], rb[4], rc[4];
    #pragma unroll
    for (int j = 0; j < 4; ++j){
      ra[j] = rec[sid[j]*4+0]; rb[j] = rec[sid[j]*4+1]; rc[j] = rec[sid[j]*4+2];
    }
    #pragma unroll
    for (int j = 0; j < 4; ++j){
      float sx[6] = {ra[j].x, ra[j].y, ra[j].z, ra[j].w, rb[j].x, rb[j].y};
      float sa[4] = {rb[j].z, rb[j].w, rc[j].x, rc[j].y};
      #pragma unroll
      for (int h = 0; h < 4; ++h){
        float e = __expf(leaky(sa[h] + ad[h]));
        den[h] += e;
        #pragma unroll
        for (int f = 0; f < 6; ++f) acc[h][f] += e * sx[f];
      }
    }
  }
  for (; i < deg; ++i){
    int s = bk[i];
    float4 a0 = rec[s*4+0], a1 = rec[s*4+1], a2 = rec[s*4+2];
    float sx[6] = {a0.x, a0.y, a0.z, a0.w, a1.x, a1.y};
    float sa[4] = {a1.z, a1.w, a2.x, a2.y};
    for (int h = 0; h < 4; ++h){
      float e = __expf(leaky(sa[h] + ad[h]));
      den[h] += e;
      for (int f = 0; f < 6; ++f) acc[h][f] += e * sx[f];
    }
  }
  float4* o = (float4*)(aggr + (size_t)n*32);
  o[0] = make_float4(acc[0][0], acc[0][1], acc[0][2], acc[0][3]);
  o[1] = make_float4(acc[0][4], acc[0][5], acc[1][0], acc[1][1]);
  o[2] = make_float4(acc[1][2], acc[1][3], acc[1][4], acc[1][5]);
  o[3] = make_float4(acc[2][0], acc[2][1], acc[2][2], acc[2][3]);
  o[4] = make_float4(acc[2][4], acc[2][5], acc[3][0], acc[3][1]);
  o[5] = make_float4(acc[3][2], acc[3][3], acc[3][4], acc[3][5]);
  o[6] = make_float4(den[0], den[1], den[2], den[3]);
}

// K4 (MFMA): per-wave 16 nodes. A-frag (helu1, bf16) computed in registers
// from aggr+W1+b1; B-frags (W2) pre-packed in lane order; no LDS, no barriers.
__global__ __launch_bounds__(256) void k4_mfma(
    const float* __restrict__ aggr, const float* __restrict__ W1,
    const float* __restrict__ b1, const unsigned short* __restrict__ Bfrag,
    const float* __restrict__ as2v, const float* __restrict__ ad2v,
    float* __restrict__ h2, float2* __restrict__ a2, int N){
  int t = threadIdx.x;
  int L = t & 63;
  int w = t >> 6;
  int base = blockIdx.x * 64;
  int m = L & 15;
  int quad = L >> 4;
  int na = base + w*16 + m;
  int nc = min(na, N-1);
  const float4* A4 = (const float4*)(aggr + (size_t)nc*32);
  float4 q0=A4[0], q1=A4[1], q2=A4[2], q3=A4[3], q4=A4[4], q5=A4[5], q6=A4[6];
  float d0=1.f/q6.x, d1=1.f/q6.y, d2=1.f/q6.z, d3=1.f/q6.w;
  float af[24];
  af[0]=q0.x*d0;  af[1]=q0.y*d0;  af[2]=q0.z*d0;  af[3]=q0.w*d0;  af[4]=q1.x*d0;  af[5]=q1.y*d0;
  af[6]=q1.z*d1;  af[7]=q1.w*d1;  af[8]=q2.x*d1;  af[9]=q2.y*d1;  af[10]=q2.z*d1; af[11]=q2.w*d1;
  af[12]=q3.x*d2; af[13]=q3.y*d2; af[14]=q3.z*d2; af[15]=q3.w*d2; af[16]=q4.x*d2; af[17]=q4.y*d2;
  af[18]=q4.z*d3; af[19]=q4.w*d3; af[20]=q5.x*d3; af[21]=q5.y*d3; af[22]=q5.z*d3; af[23]=q5.w*d3;

  f32x4 acc[4];
  #pragma unroll
  for (int ct = 0; ct < 4; ++ct) acc[ct] = (f32x4){0.f, 0.f, 0.f, 0.f};

  #pragma unroll
  for (int ks = 0; ks < 8; ++ks){
    int kb = ks*32 + quad*8;
    int kc = kb >> 6;
    const float* afk = af + kc*6;
    float4 bb0 = *(const float4*)(b1 + kb);
    float4 bb1 = *(const float4*)(b1 + kb + 4);
    float s0=bb0.x, s1=bb0.y, s2=bb0.z, s3=bb0.w;
    float s4=bb1.x, s5=bb1.y, s6=bb1.z, s7=bb1.w;
    #pragma unroll
    for (int f = 0; f < 6; ++f){
      float a = afk[f];
      float4 w0 = *(const float4*)(W1 + f*256 + kb);
      float4 w1 = *(const float4*)(W1 + f*256 + kb + 4);
      s0 += a*w0.x; s1 += a*w0.y; s2 += a*w0.z; s3 += a*w0.w;
      s4 += a*w1.x; s5 += a*w1.y; s6 += a*w1.z; s7 += a*w1.w;
    }
    ushort8 ap;
    ap[0]=f2bf(eluf(s0)); ap[1]=f2bf(eluf(s1)); ap[2]=f2bf(eluf(s2)); ap[3]=f2bf(eluf(s3));
    ap[4]=f2bf(eluf(s4)); ap[5]=f2bf(eluf(s5)); ap[6]=f2bf(eluf(s6)); ap[7]=f2bf(eluf(s7));
    bf16x8 av = __builtin_bit_cast(bf16x8, ap);
    #pragma unroll
    for (int ct = 0; ct < 4; ++ct){
      bf16x8 bv = *(const bf16x8*)(Bfrag + (size_t)(((ks*4 + ct)*64 + L) * 8));
      acc[ct] = __builtin_amdgcn_mfma_f32_16x16x32_bf16(av, bv, acc[ct], 0, 0, 0);
    }
  }

  float asv[4], adv[4];
  #pragma unroll
  for (int ct = 0; ct < 4; ++ct){ asv[ct] = as2v[ct*16 + m]; adv[ct] = ad2v[ct*16 + m]; }
  float ps[4] = {0,0,0,0}, pd[4] = {0,0,0,0};
  #pragma unroll
  for (int ct = 0; ct < 4; ++ct)
    #pragma unroll
    for (int r = 0; r < 4; ++r){
      ps[r] += acc[ct][r] * asv[ct];
      pd[r] += acc[ct][r] * adv[ct];
    }
  #pragma unroll
  for (int r = 0; r < 4; ++r){
    int nr = base + w*16 + quad*4 + r;
    if (nr < N){
      #pragma unroll
      for (int ct = 0; ct < 4; ++ct)
        h2[(size_t)nr*64 + ct*16 + m] = acc[ct][r];
    }
  }
  #pragma unroll
  for (int mask = 1; mask <= 8; mask <<= 1){
    #pragma unroll
    for (int r = 0; r < 4; ++r){
      ps[r] += __shfl_xor(ps[r], mask, 64);
      pd[r] += __shfl_xor(pd[r], mask, 64);
    }
  }
  if (m == 0){
    #pragma unroll
    for (int r = 0; r < 4; ++r){
      int nr = base + w*16 + quad*4 + r;
      if (nr < N) a2[nr] = make_float2(ps[r], pd[r]);
    }
  }
}

// K5: layer-2 aggregation only for drone dsts (first ND) + elu + MLP head.
// 4-edge batched gathers (a2 + h2 loads in flight together).
__global__ __launch_bounds__(256) void k5_out(
    const float* __restrict__ h2, const float2* __restrict__ a2,
    const int* __restrict__ cnt, const int* __restrict__ bucket,
    const float* __restrict__ b2, const float* __restrict__ fc1w,
    const float* __restrict__ fc1b, const float* __restrict__ fc2w,
    const float* __restrict__ fc2b, float* __restrict__ out, int ND){
  __shared__ float hb[4][64];
  int lane = threadIdx.x & 63;
  int w = threadIdx.x >> 6;
  int n = blockIdx.x * 4 + w;
  if (n >= ND) return;
  float2 self = a2[n];
  float adv = self.y;
  float e0 = __expf(leaky(self.x + adv));
  float den = e0;
  float acc = e0 * h2[n*64 + lane];
  int deg = min(cnt[n], CAP);
  const int* bk = bucket + (size_t)n*CAP;
  int i = 0;
  for (; i + 4 <= deg; i += 4){
    int sid[4];
    #pragma unroll
    for (int j = 0; j < 4; ++j) sid[j] = bk[i+j];
    float av[4], hv4[4];
    #pragma unroll
    for (int j = 0; j < 4; ++j){
      av[j] = a2[sid[j]].x;
      hv4[j] = h2[(size_t)sid[j]*64 + lane];
    }
    #pragma unroll
    for (int j = 0; j < 4; ++j){
      float e = __expf(leaky(av[j] + adv));
      den += e;
      acc += e * hv4[j];
    }
  }
  for (; i < deg; ++i){
    int s = bk[i];
    float e = __expf(leaky(a2[s].x + adv));
    den += e;
    acc += e * h2[(size_t)s*64 + lane];
  }
  float hv = eluf(acc / den + b2[lane]);
  hb[w][lane] = hv;               // wave-local LDS (lockstep wave64)
  float t1 = fc1b[lane];
  for (int k = 0; k < 64; ++k) t1 += hb[w][k] * fc1w[k*64 + lane];
  t1 = fmaxf(t1, 0.f);
  float p0 = t1 * fc2w[lane*2 + 0];
  float p1 = t1 * fc2w[lane*2 + 1];
  for (int o = 32; o > 0; o >>= 1){
    p0 += __shfl_down(p0, o, 64);
    p1 += __shfl_down(p1, o, 64);
  }
  if (lane == 0){
    out[n*2 + 0] = tanhf(p0 + fc2b[0]) * 2.f;
    out[n*2 + 1] = tanhf(p1 + fc2b[1]) * 2.f;
  }
}

extern "C" void kernel_launch(void* const* d_in, const int* in_sizes, int n_in,
                              void* d_out, int out_size, void* d_ws, size_t ws_size,
                              hipStream_t stream){
  const float* x    = (const float*)d_in[0];
  const int*   ei   = (const int*)d_in[1];    // harness passes integers as int32
  const float* W1   = (const float*)d_in[3];
  const float* as1  = (const float*)d_in[4];
  const float* ad1  = (const float*)d_in[5];
  const float* b1   = (const float*)d_in[6];
  const float* W2   = (const float*)d_in[7];
  const float* as2  = (const float*)d_in[8];
  const float* ad2  = (const float*)d_in[9];
  const float* b2   = (const float*)d_in[10];
  const float* fc1w = (const float*)d_in[11];
  const float* fc1b = (const float*)d_in[12];
  const float* fc2w = (const float*)d_in[13];
  const float* fc2b = (const float*)d_in[14];
  float* out = (float*)d_out;

  int N  = in_sizes[0] / 6;
  int E  = in_sizes[1] / 2;
  int ND = out_size / 2;

  char* p = (char*)d_ws;
  auto alloc = [&](size_t bytes){ void* r = (void*)p; p += (bytes + 255) & ~(size_t)255; return r; };
  int*            cnt    = (int*)           alloc((size_t)N * 4);
  int*            bucket = (int*)           alloc((size_t)N * CAP * 4);
  float4*         rec    = (float4*)        alloc((size_t)N * 64);
  float*          aggr   = (float*)         alloc((size_t)N * 128);
  float*          h2     = (float*)         alloc((size_t)N * 256);
  float2*         a2     = (float2*)        alloc((size_t)N * 8);
  unsigned short* Bfrag  = (unsigned short*)alloc(16384 * 2);

  size_t needed = (size_t)(p - (char*)d_ws);
  if (needed > ws_size) return;   // clean fail instead of GPU fault

  (void)hipMemsetAsync(cnt, 0, (size_t)N * 4, stream);
  k1_att1<<<(N + 255)/256, 256, 0, stream>>>(x, W1, as1, ad1, W2, Bfrag, rec, N);
  k2_bucket<<<(E/8 + 255)/256, 256, 0, stream>>>(ei, E, cnt, bucket);
  k3_agg1<<<(N + 255)/256, 256, 0, stream>>>(rec, cnt, bucket, aggr, N);
  k4_mfma<<<(N + 63)/64, 256, 0, stream>>>(aggr, W1, b1, Bfrag, as2, ad2, h2, a2, N);
  k5_out<<<(ND + 3)/4, 256, 0, stream>>>(h2, a2, cnt, bucket, b2,
                                         fc1w, fc1b, fc2w, fc2b, out, ND);
}

// Round 9
// 216.806 us; speedup vs baseline: 1.3249x; 1.3041x over previous
//
#include <hip/hip_runtime.h>
#include <math.h>

#define CAP 48       // max bucketed in-degree; Poisson(16), P(deg>=48) ~ 8e-11/node
#define PARTBITS 8   // 256 dsts per bin
#define BINW 256
#define NB 240       // routing blocks (phase A)
#define SEGCAP 48    // per-(bin,block) queue segment; mean 17, 7.5 sigma

typedef float f32x4 __attribute__((ext_vector_type(4)));
typedef __bf16 bf16x8 __attribute__((ext_vector_type(8)));
typedef unsigned short ushort8 __attribute__((ext_vector_type(8)));
typedef int i32x4 __attribute__((ext_vector_type(4)));
typedef int i32x2 __attribute__((ext_vector_type(2)));

__device__ __forceinline__ float leaky(float x){ return x > 0.f ? x : 0.2f * x; }
__device__ __forceinline__ float eluf(float x){ return x > 0.f ? x : __expf(x) - 1.f; }
__device__ __forceinline__ unsigned short f2bf(float f){  // RNE float->bf16
  unsigned u = __float_as_uint(f);
  u += 0x7FFF + ((u >> 16) & 1);
  return (unsigned short)(u >> 16);
}

// K1: compute vw in LDS, emit packed 64B node record:
// rec[n] = {x0..x5, as0..as3, ad0..ad3, pad, pad}  (4 x float4)
// Also (first 64 blocks) pre-pack W2 into bf16 MFMA B-fragment lane order.
__global__ __launch_bounds__(256) void k1_att1(const float* __restrict__ x,
    const float* __restrict__ W1, const float* __restrict__ as1,
    const float* __restrict__ ad1, const float* __restrict__ W2,
    unsigned short* __restrict__ Bfrag, float4* __restrict__ rec, int N){
  __shared__ float vw[48];
  int t = threadIdx.x;
  int gid = blockIdx.x * 256 + t;
  if (gid < 16384){
    int j  = gid & 7;
    int L  = (gid >> 3) & 63;
    int ct = (gid >> 9) & 3;
    int ks = gid >> 11;
    int k = ks*32 + ((L >> 4) & 3)*8 + j;
    int c = ct*16 + (L & 15);
    Bfrag[gid] = f2bf(W2[k*64 + c]);
  }
  if (t < 48){
    int side = t / 24, r = t % 24, f = r / 4, h = r % 4;
    const float* att = side ? ad1 : as1;
    float s = 0.f;
    for (int c = 0; c < 64; ++c) s += W1[f*256 + h*64 + c] * att[h*64 + c];
    vw[side*24 + f*4 + h] = s;
  }
  __syncthreads();
  int n = gid;
  if (n >= N) return;
  float xf[6];
  for (int f = 0; f < 6; ++f) xf[f] = x[n*6 + f];
  float as[4], ad[4];
  for (int h = 0; h < 4; ++h){
    float s = 0.f, d = 0.f;
    for (int f = 0; f < 6; ++f){ s += xf[f] * vw[f*4 + h]; d += xf[f] * vw[24 + f*4 + h]; }
    as[h] = s; ad[h] = d;
  }
  rec[n*4 + 0] = make_float4(xf[0], xf[1], xf[2], xf[3]);
  rec[n*4 + 1] = make_float4(xf[4], xf[5], as[0], as[1]);
  rec[n*4 + 2] = make_float4(as[2], as[3], ad[0], ad[1]);
  rec[n*4 + 3] = make_float4(ad[2], ad[3], 0.f, 0.f);
}

// K2a: route edges into per-(bin,block) queue segments; ranks from block-local
// LDS counters — ZERO global atomics. R2..R8 evidence: dur ~ WRITE_SIZE/1TBps
// for any global random scatter; so the scatter must move to LDS (k2b) and all
// global writes here are block-private runs. Queue aliases aggr+h2.
__global__ __launch_bounds__(256) void k2a_route(const int* __restrict__ ei,
    int E, int NR, i32x2* __restrict__ queue, int* __restrict__ qcnt){
  __shared__ int lcnt[512];
  int t = threadIdx.x, blk = blockIdx.x;
  for (int i = t; i < NR; i += 256) lcnt[i] = 0;
  __syncthreads();
  int E4 = E >> 2;
  const i32x4* s4 = (const i32x4*)ei;
  const i32x4* d4 = (const i32x4*)(ei + E);
  for (int i = blk*256 + t; i < E4; i += NB*256){
    i32x4 s = __builtin_nontemporal_load(s4 + i);
    i32x4 d = __builtin_nontemporal_load(d4 + i);
    #pragma unroll
    for (int j = 0; j < 4; ++j){
      int p = d[j] >> PARTBITS;
      int r = atomicAdd(&lcnt[p], 1);
      if (r < SEGCAP){ i32x2 v = {d[j], s[j]}; queue[((size_t)p*NB + blk)*SEGCAP + r] = v; }
    }
  }
  if (blk == 0 && t < (E & 3)){
    int e = E4*4 + t;
    int dd = ei[E + e], ss = ei[e];
    int p = dd >> PARTBITS;
    int r = atomicAdd(&lcnt[p], 1);
    if (r < SEGCAP){ i32x2 v = {dd, ss}; queue[((size_t)p*NB + blk)*SEGCAP + r] = v; }
  }
  __syncthreads();
  for (int i = t; i < NR; i += 256) qcnt[(size_t)i*NB + blk] = lcnt[i];
}

// K2b: one block per bin (256 dsts). Coalesced segment reads -> LDS scatter
// (49KB slab, LDS atomics) -> DENSE int4 write-out of cnt+bucket (full lines).
__global__ __launch_bounds__(1024) void k2b_build(const i32x2* __restrict__ queue,
    const int* __restrict__ qcnt, int* __restrict__ cnt, int* __restrict__ bucket){
  __shared__ int lc[BINW];
  __shared__ int lq[NB];
  __shared__ int lbuck[BINW*CAP];   // 49KB
  int t = threadIdx.x, bin = blockIdx.x;
  if (t < BINW) lc[t] = 0;
  for (int i = t; i < NB; i += 1024) lq[i] = min(qcnt[(size_t)bin*NB + i], SEGCAP);
  __syncthreads();
  const i32x2* q = queue + (size_t)bin*NB*SEGCAP;
  const int T = NB * SEGCAP;
  for (int idx = t; idx < T; idx += 1024){
    int b = idx / SEGCAP;
    int i = idx - b*SEGCAP;
    if (i < lq[b]){
      i32x2 pr = q[idx];             // (bin*NB+b)*SEGCAP+i == bin*NB*SEGCAP+idx
      int ld = pr.x & (BINW-1);
      int pos = atomicAdd(&lc[ld], 1);
      if (pos < CAP) lbuck[ld*CAP + pos] = pr.y;
    }
  }
  __syncthreads();
  const int4* bsrc = (const int4*)lbuck;
  int4* bdst = (int4*)(bucket + (size_t)bin*BINW*CAP);
  for (int i = t; i < BINW*CAP/4; i += 1024) bdst[i] = bsrc[i];
  if (t < BINW) cnt[bin*BINW + t] = lc[t];
}

// K3: per-NODE layer-1 softmax-aggregate in input space, all 4 heads at once.
// 4-edge batched gathers. Output packed 128B/node.
__global__ __launch_bounds__(256) void k3_agg1(const float4* __restrict__ rec,
    const int* __restrict__ cnt, const int* __restrict__ bucket,
    float* __restrict__ aggr, int N){
  int n = blockIdx.x * 256 + threadIdx.x;
  if (n >= N) return;
  float4 q0 = rec[n*4+0], q1 = rec[n*4+1], q2 = rec[n*4+2], q3 = rec[n*4+3];
  float xf[6] = {q0.x, q0.y, q0.z, q0.w, q1.x, q1.y};
  float as[4] = {q1.z, q1.w, q2.x, q2.y};
  float ad[4] = {q2.z, q2.w, q3.x, q3.y};
  float acc[4][6], den[4];
  for (int h = 0; h < 4; ++h){
    float e0 = __expf(leaky(as[h] + ad[h]));   // self-loop
    den[h] = e0;
    for (int f = 0; f < 6; ++f) acc[h][f] = e0 * xf[f];
  }
  int deg = min(cnt[n], CAP);
  const int* bk = bucket + (size_t)n*CAP;
  int i = 0;
  for (; i + 4 <= deg; i += 4){
    int sid[4];
    #pragma unroll
    for (int j = 0; j < 4; ++j) sid[j] = bk[i+j];
    float4 ra[4], rb[4], rc[4];
    #pragma unroll
    for (int j = 0; j < 4; ++j){
      ra[j] = rec[sid[j]*4+0]; rb[j] = rec[sid[j]*4+1]; rc[j] = rec[sid[j]*4+2];
    }
    #pragma unroll
    for (int j = 0; j < 4; ++j){
      float sx[6] = {ra[j].x, ra[j].y, ra[j].z, ra[j].w, rb[j].x, rb[j].y};
      float sa[4] = {rb[j].z, rb[j].w, rc[j].x, rc[j].y};
      #pragma unroll
      for (int h = 0; h < 4; ++h){
        float e = __expf(leaky(sa[h] + ad[h]));
        den[h] += e;
        #pragma unroll
        for (int f = 0; f < 6; ++f) acc[h][f] += e * sx[f];
      }
    }
  }
  for (; i < deg; ++i){
    int s = bk[i];
    float4 a0 = rec[s*4+0], a1 = rec[s*4+1], a2 = rec[s*4+2];
    float sx[6] = {a0.x, a0.y, a0.z, a0.w, a1.x, a1.y};
    float sa[4] = {a1.z, a1.w, a2.x, a2.y};
    for (int h = 0; h < 4; ++h){
      float e = __expf(leaky(sa[h] + ad[h]));
      den[h] += e;
      for (int f = 0; f < 6; ++f) acc[h][f] += e * sx[f];
    }
  }
  float4* o = (float4*)(aggr + (size_t)n*32);
  o[0] = make_float4(acc[0][0], acc[0][1], acc[0][2], acc[0][3]);
  o[1] = make_float4(acc[0][4], acc[0][5], acc[1][0], acc[1][1]);
  o[2] = make_float4(acc[1][2], acc[1][3], acc[1][4], acc[1][5]);
  o[3] = make_float4(acc[2][0], acc[2][1], acc[2][2], acc[2][3]);
  o[4] = make_float4(acc[2][4], acc[2][5], acc[3][0], acc[3][1]);
  o[5] = make_float4(acc[3][2], acc[3][3], acc[3][4], acc[3][5]);
  o[6] = make_float4(den[0], den[1], den[2], den[3]);
}

// K4 (MFMA): per-wave 16 nodes. A-frag (helu1, bf16) computed in registers
// from aggr+W1+b1; B-frags (W2) pre-packed in lane order; no LDS, no barriers.
__global__ __launch_bounds__(256) void k4_mfma(
    const float* __restrict__ aggr, const float* __restrict__ W1,
    const float* __restrict__ b1, const unsigned short* __restrict__ Bfrag,
    const float* __restrict__ as2v, const float* __restrict__ ad2v,
    float* __restrict__ h2, float2* __restrict__ a2, int N){
  int t = threadIdx.x;
  int L = t & 63;
  int w = t >> 6;
  int base = blockIdx.x * 64;
  int m = L & 15;
  int quad = L >> 4;
  int na = base + w*16 + m;
  int nc = min(na, N-1);
  const float4* A4 = (const float4*)(aggr + (size_t)nc*32);
  float4 q0=A4[0], q1=A4[1], q2=A4[2], q3=A4[3], q4=A4[4], q5=A4[5], q6=A4[6];
  float d0=1.f/q6.x, d1=1.f/q6.y, d2=1.f/q6.z, d3=1.f/q6.w;
  float af[24];
  af[0]=q0.x*d0;  af[1]=q0.y*d0;  af[2]=q0.z*d0;  af[3]=q0.w*d0;  af[4]=q1.x*d0;  af[5]=q1.y*d0;
  af[6]=q1.z*d1;  af[7]=q1.w*d1;  af[8]=q2.x*d1;  af[9]=q2.y*d1;  af[10]=q2.z*d1; af[11]=q2.w*d1;
  af[12]=q3.x*d2; af[13]=q3.y*d2; af[14]=q3.z*d2; af[15]=q3.w*d2; af[16]=q4.x*d2; af[17]=q4.y*d2;
  af[18]=q4.z*d3; af[19]=q4.w*d3; af[20]=q5.x*d3; af[21]=q5.y*d3; af[22]=q5.z*d3; af[23]=q5.w*d3;

  f32x4 acc[4];
  #pragma unroll
  for (int ct = 0; ct < 4; ++ct) acc[ct] = (f32x4){0.f, 0.f, 0.f, 0.f};

  #pragma unroll
  for (int ks = 0; ks < 8; ++ks){
    int kb = ks*32 + quad*8;
    int kc = kb >> 6;
    const float* afk = af + kc*6;
    float4 bb0 = *(const float4*)(b1 + kb);
    float4 bb1 = *(const float4*)(b1 + kb + 4);
    float s0=bb0.x, s1=bb0.y, s2=bb0.z, s3=bb0.w;
    float s4=bb1.x, s5=bb1.y, s6=bb1.z, s7=bb1.w;
    #pragma unroll
    for (int f = 0; f < 6; ++f){
      float a = afk[f];
      float4 w0 = *(const float4*)(W1 + f*256 + kb);
      float4 w1 = *(const float4*)(W1 + f*256 + kb + 4);
      s0 += a*w0.x; s1 += a*w0.y; s2 += a*w0.z; s3 += a*w0.w;
      s4 += a*w1.x; s5 += a*w1.y; s6 += a*w1.z; s7 += a*w1.w;
    }
    ushort8 ap;
    ap[0]=f2bf(eluf(s0)); ap[1]=f2bf(eluf(s1)); ap[2]=f2bf(eluf(s2)); ap[3]=f2bf(eluf(s3));
    ap[4]=f2bf(eluf(s4)); ap[5]=f2bf(eluf(s5)); ap[6]=f2bf(eluf(s6)); ap[7]=f2bf(eluf(s7));
    bf16x8 av = __builtin_bit_cast(bf16x8, ap);
    #pragma unroll
    for (int ct = 0; ct < 4; ++ct){
      bf16x8 bv = *(const bf16x8*)(Bfrag + (size_t)(((ks*4 + ct)*64 + L) * 8));
      acc[ct] = __builtin_amdgcn_mfma_f32_16x16x32_bf16(av, bv, acc[ct], 0, 0, 0);
    }
  }

  float asv[4], adv[4];
  #pragma unroll
  for (int ct = 0; ct < 4; ++ct){ asv[ct] = as2v[ct*16 + m]; adv[ct] = ad2v[ct*16 + m]; }
  float ps[4] = {0,0,0,0}, pd[4] = {0,0,0,0};
  #pragma unroll
  for (int ct = 0; ct < 4; ++ct)
    #pragma unroll
    for (int r = 0; r < 4; ++r){
      ps[r] += acc[ct][r] * asv[ct];
      pd[r] += acc[ct][r] * adv[ct];
    }
  #pragma unroll
  for (int r = 0; r < 4; ++r){
    int nr = base + w*16 + quad*4 + r;
    if (nr < N){
      #pragma unroll
      for (int ct = 0; ct < 4; ++ct)
        h2[(size_t)nr*64 + ct*16 + m] = acc[ct][r];
    }
  }
  #pragma unroll
  for (int mask = 1; mask <= 8; mask <<= 1){
    #pragma unroll
    for (int r = 0; r < 4; ++r){
      ps[r] += __shfl_xor(ps[r], mask, 64);
      pd[r] += __shfl_xor(pd[r], mask, 64);
    }
  }
  if (m == 0){
    #pragma unroll
    for (int r = 0; r < 4; ++r){
      int nr = base + w*16 + quad*4 + r;
      if (nr < N) a2[nr] = make_float2(ps[r], pd[r]);
    }
  }
}

// K5: layer-2 aggregation only for drone dsts (first ND) + elu + MLP head.
__global__ __launch_bounds__(256) void k5_out(
    const float* __restrict__ h2, const float2* __restrict__ a2,
    const int* __restrict__ cnt, const int* __restrict__ bucket,
    const float* __restrict__ b2, const float* __restrict__ fc1w,
    const float* __restrict__ fc1b, const float* __restrict__ fc2w,
    const float* __restrict__ fc2b, float* __restrict__ out, int ND){
  __shared__ float hb[4][64];
  int lane = threadIdx.x & 63;
  int w = threadIdx.x >> 6;
  int n = blockIdx.x * 4 + w;
  if (n >= ND) return;
  float2 self = a2[n];
  float adv = self.y;
  float e0 = __expf(leaky(self.x + adv));
  float den = e0;
  float acc = e0 * h2[n*64 + lane];
  int deg = min(cnt[n], CAP);
  const int* bk = bucket + (size_t)n*CAP;
  int i = 0;
  for (; i + 4 <= deg; i += 4){
    int sid[4];
    #pragma unroll
    for (int j = 0; j < 4; ++j) sid[j] = bk[i+j];
    float av[4], hv4[4];
    #pragma unroll
    for (int j = 0; j < 4; ++j){
      av[j] = a2[sid[j]].x;
      hv4[j] = h2[(size_t)sid[j]*64 + lane];
    }
    #pragma unroll
    for (int j = 0; j < 4; ++j){
      float e = __expf(leaky(av[j] + adv));
      den += e;
      acc += e * hv4[j];
    }
  }
  for (; i < deg; ++i){
    int s = bk[i];
    float e = __expf(leaky(a2[s].x + adv));
    den += e;
    acc += e * h2[(size_t)s*64 + lane];
  }
  float hv = eluf(acc / den + b2[lane]);
  hb[w][lane] = hv;               // wave-local LDS (lockstep wave64)
  float t1 = fc1b[lane];
  for (int k = 0; k < 64; ++k) t1 += hb[w][k] * fc1w[k*64 + lane];
  t1 = fmaxf(t1, 0.f);
  float p0 = t1 * fc2w[lane*2 + 0];
  float p1 = t1 * fc2w[lane*2 + 1];
  for (int o = 32; o > 0; o >>= 1){
    p0 += __shfl_down(p0, o, 64);
    p1 += __shfl_down(p1, o, 64);
  }
  if (lane == 0){
    out[n*2 + 0] = tanhf(p0 + fc2b[0]) * 2.f;
    out[n*2 + 1] = tanhf(p1 + fc2b[1]) * 2.f;
  }
}

extern "C" void kernel_launch(void* const* d_in, const int* in_sizes, int n_in,
                              void* d_out, int out_size, void* d_ws, size_t ws_size,
                              hipStream_t stream){
  const float* x    = (const float*)d_in[0];
  const int*   ei   = (const int*)d_in[1];    // harness passes integers as int32
  const float* W1   = (const float*)d_in[3];
  const float* as1  = (const float*)d_in[4];
  const float* ad1  = (const float*)d_in[5];
  const float* b1   = (const float*)d_in[6];
  const float* W2   = (const float*)d_in[7];
  const float* as2  = (const float*)d_in[8];
  const float* ad2  = (const float*)d_in[9];
  const float* b2   = (const float*)d_in[10];
  const float* fc1w = (const float*)d_in[11];
  const float* fc1b = (const float*)d_in[12];
  const float* fc2w = (const float*)d_in[13];
  const float* fc2b = (const float*)d_in[14];
  float* out = (float*)d_out;

  int N  = in_sizes[0] / 6;
  int E  = in_sizes[1] / 2;
  int ND = out_size / 2;
  int NR = (N + BINW - 1) >> PARTBITS;   // number of dst bins

  char* p = (char*)d_ws;
  auto alloc = [&](size_t bytes){ void* r = (void*)p; p += (bytes + 255) & ~(size_t)255; return r; };
  int*            cnt    = (int*)           alloc((size_t)NR * BINW * 4);
  int*            bucket = (int*)           alloc((size_t)NR * BINW * CAP * 4);
  float4*         rec    = (float4*)        alloc((size_t)N * 64);
  float*          aggr   = (float*)         alloc((size_t)N * 128);   // queue aliases aggr+h2
  float*          h2     = (float*)         alloc((size_t)N * 256);
  float2*         a2     = (float2*)        alloc((size_t)N * 8);     // qcnt aliases a2
  unsigned short* Bfrag  = (unsigned short*)alloc(16384 * 2);

  size_t needed = (size_t)(p - (char*)d_ws);
  if (needed > ws_size) return;   // clean fail instead of GPU fault

  // queue: [bin][block][SEGCAP] pairs; 391*240*48*8 = 34.4MB <= aggr+h2 (38.4MB)
  i32x2* queue = (i32x2*)aggr;
  int*   qcnt  = (int*)a2;        // NR*NB*4 = 375KB <= a2 (800KB)
  if ((size_t)NR * NB * SEGCAP * 8 > (size_t)N * 384) return;
  if ((size_t)NR * NB * 4 > (size_t)N * 8) return;

  k1_att1<<<(N + 255)/256, 256, 0, stream>>>(x, W1, as1, ad1, W2, Bfrag, rec, N);
  k2a_route<<<NB, 256, 0, stream>>>(ei, E, NR, queue, qcnt);
  k2b_build<<<NR, 1024, 0, stream>>>(queue, qcnt, cnt, bucket);
  k3_agg1<<<(N + 255)/256, 256, 0, stream>>>(rec, cnt, bucket, aggr, N);
  k4_mfma<<<(N + 63)/64, 256, 0, stream>>>(aggr, W1, b1, Bfrag, as2, ad2, h2, a2, N);
  k5_out<<<(ND + 3)/4, 256, 0, stream>>>(h2, a2, cnt, bucket, b2,
                                         fc1w, fc1b, fc2w, fc2b, out, ND);
}